// Round 9
// baseline (152.643 us; speedup 1.0000x reference)
//
#include <hip/hip_runtime.h>

typedef unsigned short u16;
typedef unsigned int   u32;
typedef __attribute__((ext_vector_type(8))) short short8;   // 8 x bf16 (4 VGPRs)
typedef __attribute__((ext_vector_type(16))) float f32x16;

#define MFMA32(a, b, c) __builtin_amdgcn_mfma_f32_32x32x16_bf16(a, b, c, 0, 0, 0)

constexpr int Lv = 2048, Hv = 8, Ev = 64, HE = Hv * Ev; // HE=512
constexpr float QSCALE = 0.18033688011112042f;          // 0.125 * log2(e)

__device__ __forceinline__ float bf2f(u16 u) {
    u32 x = ((u32)u) << 16;
    return __builtin_bit_cast(float, x);
}
__device__ __forceinline__ u16 f2bf(float f) {   // RNE, finite inputs
    u32 x = __builtin_bit_cast(u32, f);
    u32 r = ((x >> 16) & 1u) + 0x7fffu;
    return (u16)((x + r) >> 16);
}
// packed f32x2 -> bf16x2 (low = a, high = b), RNE
__device__ __forceinline__ u32 pkbf(float a, float b) {
#if __has_builtin(__builtin_amdgcn_cvt_pk_bf16_f32)
    typedef __attribute__((ext_vector_type(2))) __bf16 bf16x2;
    bf16x2 v = __builtin_amdgcn_cvt_pk_bf16_f32(a, b);
    return __builtin_bit_cast(u32, v);
#else
    return (u32)f2bf(a) | ((u32)f2bf(b) << 16);
#endif
}
__device__ __forceinline__ float fexp2(float x) {
#if __has_builtin(__builtin_amdgcn_exp2f)
    return __builtin_amdgcn_exp2f(x);
#else
    return exp2f(x);
#endif
}

// Runtime dtype sniff (validated: fp32 inputs detected correctly).
__device__ __forceinline__ int detect_isbf16(const u32* q32, int lane) {
    u32 w0 = q32[2 * lane];
    u32 w1 = q32[2 * lane + 1];
    u16 uu[4] = { (u16)(w0 & 0xffff), (u16)(w0 >> 16),
                  (u16)(w1 & 0xffff), (u16)(w1 >> 16) };
    int p = 0, z = 0;
#pragma unroll
    for (int j = 0; j < 4; ++j) {
        u16 mgn = (u16)(uu[j] & 0x7fff);
        int ex  = mgn >> 7;
        bool zero = (mgn == 0);
        bool pl   = zero || (ex >= 115 && ex <= 132);
        p += pl ? 1 : 0;
        if ((j & 1) == 0) z += zero ? 1 : 0;
    }
    int acc = p | (z << 16);
#pragma unroll
    for (int o = 1; o < 64; o <<= 1) acc += __shfl_xor(acc, o);
    int ps = acc & 0xffff, zs = acc >> 16;
    if (zs >= 100) return 0;
    return (ps >= 240) ? 1 : 0;
}

__device__ __forceinline__ short8 cvt8s(const float* p, float s) {
    float4 a = *(const float4*)p, b4 = *(const float4*)(p + 4);
    u32 r[4] = { pkbf(a.x * s, a.y * s), pkbf(a.z * s, a.w * s),
                 pkbf(b4.x * s, b4.y * s), pkbf(b4.z * s, b4.w * s) };
    return *(short8*)r;
}

__device__ __forceinline__ f32x16 zv16() {
    f32x16 z;
#pragma unroll
    for (int r = 0; r < 16; ++r) z[r] = 0.f;
    return z;
}

// Exchange a.hi-lanes <-> b.lo-lanes (v_permlane32_swap_b32 semantics).
__device__ __forceinline__ void plswap(u32& a, u32& b) {
#if __has_builtin(__builtin_amdgcn_permlane32_swap)
    auto r = __builtin_amdgcn_permlane32_swap(a, b, false, false);
    a = r[0]; b = r[1];
#else
    int lane = (int)(threadIdx.x & 63);
    u32 ax = (u32)__shfl_xor((int)a, 32);
    u32 bx = (u32)__shfl_xor((int)b, 32);
    bool hi = lane >= 32;
    u32 na = hi ? bx : a;
    u32 nb = hi ? b  : ax;
    a = na; b = nb;
#endif
}

// ---------------------------------------------------------------------------
// Fused full attention + l=0 local blend.
// Round-9: T15 att[2] double-pipeline on the round-3 geometry.
//   * Per iteration kt: QK(kt) MFMAs into St_cur run CONCURRENTLY with
//     exp2/pack/PV of St_prev (tile kt-1) — the two streams are data-
//     independent, so MFMA pipe (QK) overlaps VALU (softmax finish) within
//     one wave, breaking the phase convoy (VALU 50% + MFMA 18%, wall = 2x
//     VALU, measured R3-R8).
//   * St ping-pong: StA/StB static names (rule #20), iterations peeled /
//     unrolled x6 so all buffer indices and roles are compile-time.
//   * TRIPLE-buffered K/V LDS (48 KB): iter kt reads K[kt%3] (QK) and
//     V[(kt-1)%3] (PV of prev) and stores tile kt+1 into buf[(kt+1)%3] —
//     all three distinct mod 3, so one barrier per iteration suffices.
//   * Single prefetch register set (R8: 2-deep = noise), raw s_barrier +
//     lgkmcnt(0)-only (counted vmcnt from STORE dependence), setprio on
//     MFMA clusters.
// Geometry: 512 blocks x 512 thr, 128 q/block, KVBLK=64, 4 waves/SIMD.
// Wave w = (qg = w&3: 32-query sub-block) x (g = w>>2: key-half of tile).
// Split-K halves combined through LDS at the end (exact, unnormalized).
// ---------------------------------------------------------------------------
template <int ISBF>
__device__ __forceinline__ void attn_impl(
    const void* __restrict__ qv, const void* __restrict__ kv,
    const void* __restrict__ vv, const void* __restrict__ alphav,
    void* __restrict__ outv, u16* SMEM)
{
    const int tid  = threadIdx.x;       // 0..511
    const int w    = tid >> 6;          // wave 0..7
    const int lane = tid & 63;
    const int l31  = lane & 31;
    const int hi   = lane >> 5;
    const int qg   = w & 3;             // query sub-block (32 rows)
    const int g    = w >> 2;            // key-half of each 64-key tile

    // XCD-aware mapping: xcd = fid&7 handles bh in {4*xcd .. 4*xcd+3}.
    const int fid = blockIdx.x;         // 0..511
    const int bh  = (fid & 7) * 4 + ((fid >> 3) & 3);
    const int rb  = fid >> 5;           // 0..15
    const int b   = bh >> 3, h = bh & 7;
    const int row0 = rb * 128;

    const size_t bhoff = (size_t)b * Lv * HE + h * Ev;
    const u16*   q16 = (const u16*)qv + bhoff;
    const u16*   k16 = (const u16*)kv + bhoff;
    const u16*   v16 = (const u16*)vv + bhoff;
    const float* q32 = (const float*)qv + bhoff;
    const float* k32 = (const float*)kv + bhoff;
    const float* v32 = (const float*)vv + bhoff;

    u16* Klds = SMEM;            // 3 bufs x 4096 u16  [key 0..63][e], swizzled
    u16* Vt   = SMEM + 12288;    // 3 bufs x 4096 u16  [e][key 0..63], swizzled

    // Q fragments (pre-scaled). B-operand of the 32x32 S^T MFMA:
    // qf[c][j] = Qs[row0+qg*32+l31][16c + 8hi + j].
    short8 qf[4];
    {
        size_t ro = (size_t)(row0 + qg * 32 + l31) * HE + hi * 8;
        if (ISBF) {
#pragma unroll
            for (int c = 0; c < 4; ++c) {
                short8 t = *(const short8*)(q16 + ro + 16 * c);
#pragma unroll
                for (int j = 0; j < 8; ++j)
                    qf[c][j] = (short)f2bf(bf2f((u16)t[j]) * QSCALE);
            }
        } else {
#pragma unroll
            for (int c = 0; c < 4; ++c) qf[c] = cvt8s(q32 + ro + 16 * c, QSCALE);
        }
    }

    f32x16 O[2];
    O[0] = zv16(); O[1] = zv16();
    f32x16 StA = zv16(), StB = zv16();   // ping-pong score states
    float psum = 0.f;   // per-lane partial row sum (query l31, this g/hi slice)

    // K staging (512 threads, one 64-key tile): chunk tid: key=tid>>3,
    // slot=tid&7; XOR swizzle folded into GLOBAL offset, LDS write linear.
    const int kkey = tid >> 3, ksl = tid & 7;
    const int koff = kkey * HE + ((ksl ^ (kkey & 7)) * 8);
    // V staging: key-pair (2*pp, 2*pp+1), e-quad eq (4 e values).
    const int eq = tid & 15, pp = tid >> 4;      // pp 0..31
    const int kcv = pp >> 2, pq = pp & 3;

    // ---- prefetch registers (single set) ----
    float4 kfa, kfb, vfa, vfb;          // fp32 path
    uint4  kru; uint2 vru0, vru1;       // bf16 path

#define LOAD_TILE(KT)                                                          \
    do {                                                                       \
        size_t kb_ = (size_t)(KT) * 64 * HE;                                   \
        if (ISBF) {                                                            \
            kru  = *(const uint4*)(k16 + kb_ + koff);                          \
            const u16* vp_ = v16 + kb_ + (size_t)(2 * pp) * HE + eq * 4;       \
            vru0 = *(const uint2*)vp_;                                         \
            vru1 = *(const uint2*)(vp_ + HE);                                  \
        } else {                                                               \
            const float* kp_ = k32 + kb_ + koff;                               \
            kfa = *(const float4*)kp_;                                         \
            kfb = *(const float4*)(kp_ + 4);                                   \
            const float* vp_ = v32 + kb_ + (size_t)(2 * pp) * HE + eq * 4;     \
            vfa = *(const float4*)vp_;                                         \
            vfb = *(const float4*)(vp_ + HE);                                  \
        }                                                                      \
    } while (0)

#define STORE_TILE(BS)                                                         \
    do {                                                                       \
        u16* KB = Klds + (BS) * 4096;                                          \
        u16* VB = Vt   + (BS) * 4096;                                          \
        if (ISBF) {                                                            \
            *(uint4*)&KB[tid * 8] = kru;                                       \
            const u16* a0_ = (const u16*)&vru0;                                \
            const u16* a1_ = (const u16*)&vru1;                                \
            _Pragma("unroll")                                                  \
            for (int j = 0; j < 4; ++j) {                                      \
                int e_  = eq * 4 + j;                                          \
                int sl_ = kcv ^ ((e_ + (e_ >> 3)) & 7);                        \
                u32 val_ = (u32)a0_[j] | ((u32)a1_[j] << 16);                  \
                *(u32*)&VB[e_ * 64 + sl_ * 8 + pq * 2] = val_;                 \
            }                                                                  \
        } else {                                                               \
            u32 kk_[4] = { pkbf(kfa.x, kfa.y), pkbf(kfa.z, kfa.w),             \
                           pkbf(kfb.x, kfb.y), pkbf(kfb.z, kfb.w) };           \
            *(uint4*)&KB[tid * 8] = *(uint4*)kk_;                              \
            float t0_[4] = {vfa.x, vfa.y, vfa.z, vfa.w};                       \
            float t1_[4] = {vfb.x, vfb.y, vfb.z, vfb.w};                       \
            _Pragma("unroll")                                                  \
            for (int j = 0; j < 4; ++j) {                                      \
                int e_  = eq * 4 + j;                                          \
                int sl_ = kcv ^ ((e_ + (e_ >> 3)) & 7);                        \
                *(u32*)&VB[e_ * 64 + sl_ * 8 + pq * 2] = pkbf(t0_[j], t1_[j]); \
            }                                                                  \
        }                                                                      \
    } while (0)

    // QK of tile KT into ST, reading K buffer BQ.
#define QK_ST(ST, BQ)                                                          \
    do {                                                                       \
        const u16* Kb = Klds + (BQ) * 4096;                                    \
        (ST) = zv16();                                                         \
        __builtin_amdgcn_s_setprio(1);                                         \
        _Pragma("unroll")                                                      \
        for (int c = 0; c < 4; ++c) {                                          \
            int sl = (2 * c + hi) ^ (l31 & 7);                                 \
            short8 kf = *(const short8*)&Kb[(g * 32 + l31) * 64 + sl * 8];     \
            (ST) = MFMA32(kf, qf[c], (ST));                                    \
        }                                                                      \
        __builtin_amdgcn_s_setprio(0);                                         \
    } while (0)

    // Softmax finish + PV of the tile whose scores sit in SP; V buffer BP.
#define FIN_ST(SP, BP)                                                         \
    do {                                                                       \
        const u16* Vb = Vt + (BP) * 4096;                                      \
        _Pragma("unroll")                                                      \
        for (int r = 0; r < 16; ++r) (SP)[r] = fexp2((SP)[r]);                 \
        _Pragma("unroll")                                                      \
        for (int r = 0; r < 16; ++r) psum += (SP)[r];                          \
        u32 c8[8];                                                             \
        _Pragma("unroll")                                                      \
        for (int q = 0; q < 8; ++q) c8[q] = pkbf((SP)[2 * q], (SP)[2 * q + 1]);\
        _Pragma("unroll")                                                      \
        for (int t = 0; t < 2; ++t) {                                          \
            u32 a0 = c8[4 * t + 0], a1 = c8[4 * t + 1];                        \
            u32 a2 = c8[4 * t + 2], a3 = c8[4 * t + 3];                        \
            plswap(a0, a2);                                                    \
            plswap(a1, a3);                                                    \
            u32 pw_[4] = { a0, a1, a2, a3 };                                   \
            short8 pa = *(short8*)pw_;                                         \
            int ks = 2 * g + t;                                                \
            __builtin_amdgcn_s_setprio(1);                                     \
            _Pragma("unroll")                                                  \
            for (int et = 0; et < 2; ++et) {                                   \
                int e  = et * 32 + l31;                                        \
                int sl = (2 * ks + hi) ^ ((e + (e >> 3)) & 7);                 \
                short8 vf = *(const short8*)&Vb[e * 64 + sl * 8];              \
                O[et] = MFMA32(pa, vf, O[et]);                                 \
            }                                                                  \
            __builtin_amdgcn_s_setprio(0);                                     \
        }                                                                      \
    } while (0)

#define ENDBAR()                                                               \
    do {                                                                       \
        asm volatile("s_waitcnt lgkmcnt(0)" ::: "memory");                     \
        __builtin_amdgcn_s_barrier();                                          \
    } while (0)

    // Steady-state iteration kt (1..30): LOAD(kt+1); QK(kt)->SC; finish
    // tile kt-1 from SP (V buf BP); STORE tile kt+1 -> buf BS; barrier.
#define BODY(KT, BQ, BP, BS, SC, SP)                                           \
    do {                                                                       \
        LOAD_TILE((KT) + 1);                                                   \
        QK_ST(SC, BQ);                                                         \
        FIN_ST(SP, BP);                                                        \
        STORE_TILE(BS);                                                        \
        ENDBAR();                                                              \
    } while (0)

    // ---- prologue: tile 0 -> buf 0 ----
    LOAD_TILE(0);
    STORE_TILE(0);
    ENDBAR();

    // ---- kt = 0 (no previous tile to finish) ----
    LOAD_TILE(1);
    QK_ST(StA, 0);
    STORE_TILE(1);
    ENDBAR();

    // ---- kt = 1..30, unrolled x6 (buffer indices & St roles static) ----
    for (int j = 0; j < 5; ++j) {
        const int kt = 6 * j + 1;
        BODY(kt + 0, 1, 0, 2, StB, StA);   // kt%6==1
        BODY(kt + 1, 2, 1, 0, StA, StB);   // kt%6==2
        BODY(kt + 2, 0, 2, 1, StB, StA);   // kt%6==3
        BODY(kt + 3, 1, 0, 2, StA, StB);   // kt%6==4
        BODY(kt + 4, 2, 1, 0, StB, StA);   // kt%6==5
        BODY(kt + 5, 0, 2, 1, StA, StB);   // kt%6==0
    }

    // ---- kt = 31: QK + finish tile 30; no further staging ----
    QK_ST(StB, 1);
    FIN_ST(StA, 0);
    // ---- finish tile 31 ----
    FIN_ST(StB, 1);
#undef LOAD_TILE
#undef STORE_TILE
#undef QK_ST
#undef FIN_ST
#undef ENDBAR
#undef BODY

    // ---- combine the two key-halves through LDS (exact, unnormalized) ----
    __syncthreads();                              // all K/V tile reads done
    float pst = psum + __shfl_xor(psum, 32);      // row sum over this half
    float* cb = (float*)SMEM;                     // tiles dead; reuse as f32
    const int cbase = qg * 2368 + lane * 36;      // 36 f32 stride: 16B-aligned

    if (g == 1) {
        union { f32x16 v; float4 q4[4]; } u;
        u.v = O[0];
#pragma unroll
        for (int i = 0; i < 4; ++i) *(float4*)&cb[cbase + 4 * i] = u.q4[i];
        u.v = O[1];
#pragma unroll
        for (int i = 0; i < 4; ++i) *(float4*)&cb[cbase + 16 + 4 * i] = u.q4[i];
        cb[qg * 2368 + 2304 + lane] = pst;
    }

    // ---- l=0 local attention (wave 0 = qg0/g0 of rb==0 blocks) ----
    float locv[2] = {0.f, 0.f};
    float wgt = 0.f;
    const bool w0blk = (rb == 0) && (w == 0);
    if (w0blk) {
        const int e = lane;
        const size_t base = bhoff + e;
#define LDIN(p, i) (ISBF ? bf2f(((const u16*)(p))[i]) : ((const float*)(p))[i])
        float qe = LDIN(qv, base);
        float s[9];
#pragma unroll
        for (int j = 0; j < 9; ++j) {
            float prod = qe * LDIN(kv, base + (size_t)j * HE);
#pragma unroll
            for (int o = 1; o < 64; o <<= 1) prod += __shfl_xor(prod, o);
            s[j] = prod * 0.125f;
        }
        float mx = s[0];
#pragma unroll
        for (int j = 1; j < 9; ++j) mx = fmaxf(mx, s[j]);
        float we[9];
#pragma unroll
        for (int j = 0; j < 9; ++j) we[j] = expf(s[j] - mx);
        float denom = 9.f * we[0];
        float acc   = 9.f * we[0] * LDIN(vv, base);
#pragma unroll
        for (int j = 1; j < 9; ++j) {
            denom += we[j];
            acc   += we[j] * LDIN(vv, base + (size_t)j * HE);
        }
        float loc = acc / denom;

        float a;
        if (ISBF) {
            a = bf2f(((const u16*)alphav)[0]);
            if (!(a >= 0.0f && a <= 1.0f)) {
                float af = ((const float*)alphav)[0];
                if (af >= 0.0f && af <= 1.0f) a = af;
            }
        } else {
            a = ((const float*)alphav)[0];
            if (!(a >= 0.0f && a <= 1.0f)) {
                float ab = bf2f(((const u16*)alphav)[0]);
                if (ab >= 0.0f && ab <= 1.0f) a = ab;
            }
        }
        wgt = 1.f / (1.f + expf(-a));
#pragma unroll
        for (int et = 0; et < 2; ++et) locv[et] = __shfl(loc, et * 32 + l31);
#undef LDIN
    }

    __syncthreads();                              // partials visible
    if (g != 0) return;

    // ---- g==0 waves: add partner partials, normalize, blend, store ----
    float pstp = cb[qg * 2368 + 2304 + lane];
#pragma unroll
    for (int r = 0; r < 16; ++r) {
        O[0][r] += cb[cbase + r];
        O[1][r] += cb[cbase + 16 + r];
    }
    float invv = 1.0f / (pst + pstp);

#pragma unroll
    for (int rg = 0; rg < 4; ++rg) {
#pragma unroll
        for (int rr = 0; rr < 4; ++rr) {
            const int reg = rg * 4 + rr;
            const int rl  = rr + 8 * rg + 4 * hi;       // local output row
            float inv = __shfl(invv, rl);               // broadcast from lane rl
            int row = row0 + qg * 32 + rl;
            size_t oo = (size_t)(b * Lv + row) * HE + h * Ev + l31;
            bool blend = w0blk && (rl == 0);
#pragma unroll
            for (int et = 0; et < 2; ++et) {
                float res = O[et][reg] * inv;
                if (blend) res = wgt * res + (1.f - wgt) * locv[et];
                if (ISBF) ((u16*)outv)[oo + et * 32] = f2bf(res);
                else      ((float*)outv)[oo + et * 32] = res;
            }
        }
    }
}

__global__ __launch_bounds__(512, 4) void attn_kernel(
    const void* __restrict__ qv, const void* __restrict__ kv,
    const void* __restrict__ vv, const void* __restrict__ alphav,
    void* __restrict__ outv)
{
    // [0,24K) u16: K tiles (3 bufs x 64x64). [24K,48K) u16: V tiles (3 bufs).
    // Whole buffer reused as float scratch (9472 f32) for split-K combine.
    __shared__ u16 SMEM[24576];

    const int isbf = detect_isbf16((const u32*)qv, threadIdx.x & 63);
    if (isbf) attn_impl<1>(qv, kv, vv, alphav, outv, SMEM);
    else      attn_impl<0>(qv, kv, vv, alphav, outv, SMEM);
}

extern "C" void kernel_launch(void* const* d_in, const int* in_sizes, int n_in,
                              void* d_out, int out_size, void* d_ws, size_t ws_size,
                              hipStream_t stream) {
    hipLaunchKernelGGL(attn_kernel, dim3(512), dim3(512), 0, stream,
                       d_in[0], d_in[1], d_in[2], d_in[3], d_out);
}